// Round 8
// baseline (40.960 us; speedup 1.0000x reference)
//
#include <hip/hip_runtime.h>

// NormalComputer: out[b,:,i,j] = normalize(cross(up - down, right - left))
// Identity: sum of 4 reference cross products == cross(up-down, right-left);
// center cancels; idx input never read (clamped indices recomputed from i,j).
//
// R8: final A/B on px/thread sweep (1px=33.4, 4px=35.0, 8px=42.4 us):
//     2 px/thread with float2 loads/stores — halves per-px load instructions
//     vs 1px (left/right interior neighbors come from the md float2) while
//     keeping 4M threads / 16384 blocks. XCD slab swizzle kept (batch b -> XCD b).

#define HH 1024
#define WW 1024
#define BB 8
#define HW (HH * WW)

typedef float floatx2 __attribute__((ext_vector_type(2)));

__global__ __launch_bounds__(256)
void normal_kernel(const float* __restrict__ in, float* __restrict__ out) {
    // 16384 blocks; bijective chunked XCD swizzle: XCD x gets blocks
    // [x*2048, (x+1)*2048) == batch-image x (2048 blocks of 512 px each).
    const int nb = (blockIdx.x & 7) * 2048 + (blockIdx.x >> 3);
    const int b  = nb >> 11;                       // batch (== XCD index)
    const int p2 = ((nb & 2047) << 8) | threadIdx.x;  // pixel-pair index
    const int i  = p2 >> 9;                        // row (512 pairs per row)
    const int j0 = (p2 & 511) << 1;                // starting col (even)

    const int iu = (i > 0)      ? i - 1 : 0;
    const int id = (i < HH - 1) ? i + 1 : HH - 1;
    const int jL = (j0 > 0) ? j0 - 1 : 0;              // clamped left of j0
    const int jR = (j0 + 2 < WW) ? j0 + 2 : WW - 1;    // clamped right of j0+1

    const float* base = in + (size_t)b * 3 * HW;

    float ax[2][3], cx[2][3];
#pragma unroll
    for (int ch = 0; ch < 3; ++ch) {
        const float* pl = base + (size_t)ch * HW;
        const floatx2 up = *(const floatx2*)(pl + iu * WW + j0);
        const floatx2 dn = *(const floatx2*)(pl + id * WW + j0);
        const floatx2 md = *(const floatx2*)(pl + i  * WW + j0);
        const float lf  = pl[i * WW + jL];
        const float rt  = pl[i * WW + jR];

        ax[0][ch] = up.x - dn.x;
        ax[1][ch] = up.y - dn.y;
        cx[0][ch] = md.y - lf;
        cx[1][ch] = rt   - md.x;
    }

    floatx2 ox, oy, oz;
#pragma unroll
    for (int k = 0; k < 2; ++k) {
        const float nx = ax[k][1] * cx[k][2] - ax[k][2] * cx[k][1];
        const float ny = ax[k][2] * cx[k][0] - ax[k][0] * cx[k][2];
        const float nz = ax[k][0] * cx[k][1] - ax[k][1] * cx[k][0];
        const float norm = sqrtf(nx * nx + ny * ny + nz * nz);
        const float inv  = 1.0f / fmaxf(norm, 1e-6f);
        ox[k] = nx * inv; oy[k] = ny * inv; oz[k] = nz * inv;
    }

    float* ob = out + (size_t)b * 3 * HW + i * WW + j0;
    *(floatx2*)(ob)          = ox;
    *(floatx2*)(ob + HW)     = oy;
    *(floatx2*)(ob + 2 * HW) = oz;
}

extern "C" void kernel_launch(void* const* d_in, const int* in_sizes, int n_in,
                              void* d_out, int out_size, void* d_ws, size_t ws_size,
                              hipStream_t stream) {
    const float* in = (const float*)d_in[0];
    float* out = (float*)d_out;
    const int grid = BB * HW / (256 * 2);     // 16384 blocks, 2 px/thread
    normal_kernel<<<grid, 256, 0, stream>>>(in, out);
}